// Round 13
// baseline (260.162 us; speedup 1.0000x reference)
//
#include <hip/hip_runtime.h>
#include <hip/hip_bf16.h>
#include <stdint.h>

typedef __attribute__((ext_vector_type(4))) float f32x4;
typedef __attribute__((ext_vector_type(16))) float f32x16;
typedef __attribute__((ext_vector_type(8))) short bf16x8;
typedef __attribute__((ext_vector_type(4))) uint32_t u32x4;

#define KD 512
#define ND 512

// pack two fp32 -> one u32 of two bf16 (round-half-away via +0x8000; v_perm
// grabs the high 16 bits of each)
__device__ __forceinline__ uint32_t pk_bf16(float lo, float hi) {
  uint32_t ulo = __float_as_uint(lo) + 0x8000u;
  uint32_t uhi = __float_as_uint(hi) + 0x8000u;
  return __builtin_amdgcn_perm(uhi, ulo, 0x07060302u);
}

// Fragment-ready W repack (validated R9): w (512x512 fp32, w[k][d]) -> wt.
// 16B chunk (ks, d, hi) holds bf16 k = ks*16 + hi*8 + 0..7 of column d.
// A wf load (fixed ks, 32 consecutive d, hi = lane>>5) is ONE contiguous
// 1KB wave load.
__global__ void wt_kernel(const float* __restrict__ w, uint16_t* __restrict__ wt) {
  __shared__ float tile[32][33];
  const int bx = blockIdx.x, by = blockIdx.y;
  const int tx = threadIdx.x, ty = threadIdx.y;  // (32, 8)
#pragma unroll
  for (int i = 0; i < 32; i += 8)
    tile[ty + i][tx] = w[(bx * 32 + ty + i) * ND + by * 32 + tx];
  __syncthreads();
#pragma unroll
  for (int i = 0; i < 32; i += 8) {
    uint32_t u = __float_as_uint(tile[tx][ty + i]);
    uint32_t r = (u + 0x7FFFu + ((u >> 16) & 1u)) >> 16;  // RNE
    const int d = by * 32 + ty + i;
    const int k = bx * 32 + tx;
    wt[((k >> 4) * 512 + d) * 16 + ((k >> 3) & 1) * 8 + (k & 7)] = (uint16_t)r;
  }
}

// Pipelined panel GEMM (R10 structure, ring bug fixed: depth-4 W ring so
// prefetch distance 3 never collides with the consuming slot).
// Grid 512 (all co-resident, 2 blocks/CU), 512 threads (8 waves). Each block:
// 128 rows = 2 panels of 64; K=512 in 4 chunks of 128. Per iteration (8 total):
//   barrier -> ISSUE(it+1) global loads -> COMPUTE(it) [8ks x {2 coalesced W
//   ring loads, 2 swizzled ds_reads, 4 mfma_32x32x16}] -> COMMIT(it+1)
//   pack+ds_write -> epilogue at panel end.
__global__ __launch_bounds__(512, 4) void gemm_kernel(
    const float* __restrict__ x, const uint16_t* __restrict__ wt,
    float* __restrict__ out) {
  __shared__ uint16_t As[2][64 * 128];  // 2 x 16KB, row stride 256B, slot-XOR swizzle

  const int tid = threadIdx.x;
  const int lane = tid & 63;
  const int l31 = lane & 31, hi = lane >> 5;
  const int wid = tid >> 6;  // 0..7: col slice [wid*64, wid*64+64)
  const int mblk = blockIdx.x * 128;

  // ---- staging mapping: thread -> (row sr, slots sc, sc+8) ----
  const int sr = tid >> 3;  // 0..63 output-local row
  const int sc = tid & 7;   // 16B-slot base within 128-k chunk (16 slots/row)
  const int prow = ((sr & 31) << 1) + (sr >> 5);  // patch-expansion perm
  const char* xrow = (const char*)x + (size_t)(mblk + prow) * 2048 + sc * 32;
  const int srx = (sr & 7) << 1;
  const int dOff0 = sr * 256 + ((sc) ^ srx) * 16;
  const int dOff1 = sr * 256 + ((sc + 8) ^ srx) * 16;

  // ---- compute mapping ----
  const char* wb = (const char*)wt;
  uint32_t wOff[2];
#pragma unroll
  for (int tn = 0; tn < 2; ++tn)
    wOff[tn] = (uint32_t)(wid * 64 + tn * 32 + l31) * 32 + hi * 16;
  uint32_t aOff[2];
#pragma unroll
  for (int rg = 0; rg < 2; ++rg) aOff[rg] = (uint32_t)(rg * 32 + l31) * 256;
  const uint32_t ax = (l31 & 7) << 1;

  f32x16 acc[2][2];
#pragma unroll
  for (int rg = 0; rg < 2; ++rg)
#pragma unroll
    for (int tn = 0; tn < 2; ++tn)
#pragma unroll
      for (int e = 0; e < 16; ++e) acc[rg][tn][e] = 0.f;

  f32x4 sv0, sv1, sv2, sv3;  // in-flight stage registers (T14 issue-early)

  auto ISSUE = [&](int it) {
    const char* s = xrow + (it >> 2) * (64 * 2048) + (it & 3) * 512;
    sv0 = *(const f32x4*)(s);
    sv1 = *(const f32x4*)(s + 16);
    sv2 = *(const f32x4*)(s + 256);
    sv3 = *(const f32x4*)(s + 256 + 16);
  };
  auto COMMIT = [&](int it) {
    char* d = (char*)As[it & 1];
    u32x4 p0 = {pk_bf16(sv0.x, sv0.y), pk_bf16(sv0.z, sv0.w),
                pk_bf16(sv1.x, sv1.y), pk_bf16(sv1.z, sv1.w)};
    u32x4 p1 = {pk_bf16(sv2.x, sv2.y), pk_bf16(sv2.z, sv2.w),
                pk_bf16(sv3.x, sv3.y), pk_bf16(sv3.z, sv3.w)};
    *(u32x4*)(d + dOff0) = p0;
    *(u32x4*)(d + dOff1) = p1;
  };

  ISSUE(0);
  COMMIT(0);

#pragma unroll
  for (int it = 0; it < 8; ++it) {
    __syncthreads();  // buf[it&1] staged & prior readers of buf[(it+1)&1] done
    if (it < 7) ISSUE(it + 1);

    // ---- COMPUTE(it): 8 ks from As[it&1], W via depth-4 ring (dist 3) ----
    {
      const char* ab = (const char*)As[it & 1];
      const int gks0 = (it & 3) * 8;
      bf16x8 wf[4][2];  // ring slot = ks & 3; prefetch (ks+3)&3 != ks&3
#pragma unroll
      for (int kp = 0; kp < 3; ++kp)
#pragma unroll
        for (int tn = 0; tn < 2; ++tn)
          wf[kp][tn] =
              *(const bf16x8*)(wb + (size_t)(gks0 + kp) * 16384 + wOff[tn]);
#pragma unroll
      for (int ksl = 0; ksl < 8; ++ksl) {
        if (ksl < 5) {
#pragma unroll
          for (int tn = 0; tn < 2; ++tn)
            wf[(ksl + 3) & 3][tn] = *(const bf16x8*)(
                wb + (size_t)(gks0 + ksl + 3) * 16384 + wOff[tn]);
        }
        bf16x8 af[2];
#pragma unroll
        for (int rg = 0; rg < 2; ++rg) {
          const uint32_t s = ((uint32_t)(2 * ksl + hi)) ^ ax;
          af[rg] = *(const bf16x8*)(ab + aOff[rg] + s * 16);
        }
#pragma unroll
        for (int rg = 0; rg < 2; ++rg)
#pragma unroll
          for (int tn = 0; tn < 2; ++tn)
            acc[rg][tn] = __builtin_amdgcn_mfma_f32_32x32x16_bf16(
                wf[ksl & 3][tn], af[rg], acc[rg][tn], 0, 0, 0);
      }
    }

    if (it < 7) COMMIT(it + 1);

    if ((it & 3) == 3) {
      // ---- epilogue panel p: D col(lane&31)=x-row, row-map = W-col ----
      const int p = it >> 2;
#pragma unroll
      for (int rg = 0; rg < 2; ++rg) {
        float* op =
            out + (size_t)(mblk + p * 64 + rg * 32 + l31) * ND + wid * 64;
#pragma unroll
        for (int tn = 0; tn < 2; ++tn) {
#pragma unroll
          for (int q = 0; q < 4; ++q) {
            f32x4 v = {acc[rg][tn][q * 4 + 0], acc[rg][tn][q * 4 + 1],
                       acc[rg][tn][q * 4 + 2], acc[rg][tn][q * 4 + 3]};
            *(f32x4*)(op + tn * 32 + q * 8 + hi * 4) = v;
          }
        }
      }
      if (it == 3) {
#pragma unroll
        for (int rg = 0; rg < 2; ++rg)
#pragma unroll
          for (int tn = 0; tn < 2; ++tn)
#pragma unroll
            for (int e = 0; e < 16; ++e) acc[rg][tn][e] = 0.f;
      }
    }
  }
}

extern "C" void kernel_launch(void* const* d_in, const int* in_sizes, int n_in,
                              void* d_out, int out_size, void* d_ws, size_t ws_size,
                              hipStream_t stream) {
  const float* x = (const float*)d_in[0];  // (32, 1024, 1024) fp32
  const float* w = (const float*)d_in[1];  // (512, 512) fp32
  float* out = (float*)d_out;              // (32, 2048, 512) fp32
  uint16_t* wt = (uint16_t*)d_ws;          // 512KB bf16 fragment-layout scratch

  wt_kernel<<<dim3(16, 16), dim3(32, 8), 0, stream>>>(w, wt);
  gemm_kernel<<<dim3(512), dim3(512), 0, stream>>>(x, wt, out);
}